// Round 6
// baseline (343.261 us; speedup 1.0000x reference)
//
#include <hip/hip_runtime.h>

// sigma = 1e-4  ->  1/sigma = 1e4
#define INV_SIGMA 1.0e4f
#define ROUNDS 8   // chunks per thread; 256 threads * 8 = 2048 chunks/block

typedef float v4f __attribute__((ext_vector_type(4)));
typedef int   v4i __attribute__((ext_vector_type(4)));

__device__ __forceinline__ float one_minus_prob(float d, int f) {
    // (f >= 0) ? 1 - sigmoid(-d/sigma) : 1   ==   (f >= 0) ? sigmoid(d/sigma) : 1
    float s = 1.0f / (1.0f + __expf(-d * INV_SIGMA));
    return (f >= 0) ? s : 1.0f;
}

// R6: cache-policy experiment on the proven 78us R0 structure. Ledger: MLP
// depth (R0==R1), forced asm bursts (R2 regressed), pixel-per-thread (R4
// regressed), TRANS pipe (R5 flat; R4's estimate had a /64 arithmetic bug)
// are all falsified. Through-cache traffic at 78us = 417MB -> 5.34 TB/s
// combined, but HBM only 2.9 TB/s: latency-limited, so average miss latency
// is the lever. Old code marked EVERYTHING nontemporal -- including zbuf,
// a 128MB stream (fits the 256MB LLC!) re-read every iteration at 4B/64B
// density, which nt condemns to ~900cy HBM latency each pass. Flip: zbuf
// loads allocate normally (LLC-resident across iterations -> ~350cy), while
// single-use dists/p2f stay nt so they don't thrash it. Math and layout are
// bit-identical to the 78us baseline.
__global__ __launch_bounds__(256) void SelfShader_9921374454199_kernel(
    const float* __restrict__ zbuf,
    const float* __restrict__ dists,
    const int*   __restrict__ p2f,
    float*       __restrict__ out,
    long long nChunks)  // 4 * N*H*W
{
    const int t = threadIdx.x;
    const long long cbase = (long long)blockIdx.x * (256 * ROUNDS) + t;

    const v4f* d4 = reinterpret_cast<const v4f*>(dists);
    const v4i* f4 = reinterpret_cast<const v4i*>(p2f);

    if (cbase + (ROUNDS - 1) * 256 < nChunks) {
        v4f   d[ROUNDS];
        v4i   f[ROUNDS];
        float z[ROUNDS];
#pragma unroll
        for (int r = 0; r < ROUNDS; ++r) {
            long long c = cbase + r * 256;
            d[r] = __builtin_nontemporal_load(d4 + c);
            f[r] = __builtin_nontemporal_load(f4 + c);
            // zbuf[pixel*16], pixel = c>>2; 4 lanes share an address (coalesces).
            // REGULAR load: let these lines allocate + persist in LLC.
            z[r] = zbuf[(c >> 2) << 4];
        }
#pragma unroll
        for (int r = 0; r < ROUNDS; ++r) {
            long long c = cbase + r * 256;
            float prod = one_minus_prob(d[r].x, f[r].x) * one_minus_prob(d[r].y, f[r].y)
                       * one_minus_prob(d[r].z, f[r].z) * one_minus_prob(d[r].w, f[r].w);
            // combine the 4 quarter-products of this pixel (lanes 4k..4k+3)
            prod *= __shfl_xor(prod, 1, 4);
            prod *= __shfl_xor(prod, 2, 4);
            float v = ((t & 3) == 3) ? (1.0f - prod) : z[r];
            __builtin_nontemporal_store(v, out + c);
        }
    } else {
        // tail path (never taken for the bench shape: 8.39M chunks / 2048 exact)
        for (int r = 0; r < ROUNDS; ++r) {
            long long c = cbase + r * 256;
            if (c >= nChunks) break;
            v4f   dd = d4[c];
            v4i   ff = f4[c];
            float zz = zbuf[(c >> 2) << 4];
            float prod = one_minus_prob(dd.x, ff.x) * one_minus_prob(dd.y, ff.y)
                       * one_minus_prob(dd.z, ff.z) * one_minus_prob(dd.w, ff.w);
            prod *= __shfl_xor(prod, 1, 4);
            prod *= __shfl_xor(prod, 2, 4);
            out[c] = ((t & 3) == 3) ? (1.0f - prod) : zz;
        }
    }
}

extern "C" void kernel_launch(void* const* d_in, const int* in_sizes, int n_in,
                              void* d_out, int out_size, void* d_ws, size_t ws_size,
                              hipStream_t stream) {
    const float* zbuf  = (const float*)d_in[0];
    const float* dists = (const float*)d_in[1];
    const int*   p2f   = (const int*)d_in[2];
    float*       out   = (float*)d_out;

    long long nChunks = (long long)in_sizes[0] / 4;  // 4 float4 chunks per pixel (K=16)
    const long long chunksPerBlock = 256LL * ROUNDS;
    int grid = (int)((nChunks + chunksPerBlock - 1) / chunksPerBlock);
    SelfShader_9921374454199_kernel<<<grid, 256, 0, stream>>>(zbuf, dists, p2f, out, nChunks);
}